// Round 10
// baseline (295.312 us; speedup 1.0000x reference)
//
#include <hip/hip_runtime.h>
#include <hip/hip_bf16.h>
#include <math.h>

// Problem constants (CompactPointMamba: B=4, N=2048, E=128)
#define BATCH 4
#define NPTS  2048
#define L     4096      // 2*NPTS after concat of hilbert/trans orders
#define E     128
#define DI    256       // E*EXP
#define DS    16
#define DRR   8         // (E+15)//16
#define DCV   4
#define NBLK  2
#define NC    40
#define XDW   40        // DR + 2*DS
#define ROWS  (BATCH*L) // 16384
#define CH    32        // scan chunk length (32 proven best: R5=276.6 vs R6 CH=16=290.5)
#define NCH   128       // L / CH

typedef unsigned short u16;
typedef short short8 __attribute__((ext_vector_type(8)));
typedef float f32x4v __attribute__((ext_vector_type(4)));

// bf16 round-to-nearest-even helpers
__device__ __forceinline__ u16 f2bf(float x) {
  unsigned u = __float_as_uint(x);
  u = u + 0x7FFFu + ((u >> 16) & 1u);
  return (u16)(u >> 16);
}
__device__ __forceinline__ float bf2f(u16 h) {
  return __uint_as_float(((unsigned)h) << 16);
}
// fast softplus: ln(1+e^x) = ln2 * log2(1 + 2^(x*log2e))
__device__ __forceinline__ float softplusf(float x) {
  if (x > 20.f) return x;
  float t = __builtin_amdgcn_exp2f(x * 1.44269504f);
  return 0.69314718f * __builtin_amdgcn_logf(1.f + t);
}

// ---------------------------------------------------------------- embed + LN(block0) + split, row per wave
__global__ void embed_ln_split(const float* __restrict__ x,
                               const int* __restrict__ oh, const int* __restrict__ ot,
                               const float* __restrict__ pe_w, const float* __restrict__ pe_b,
                               const float* __restrict__ gamma, const float* __restrict__ beta,
                               const float* __restrict__ g, const float* __restrict__ bb,
                               float* __restrict__ h, u16* __restrict__ dhi, u16* __restrict__ dlo) {
  int wave = threadIdx.x >> 6;
  int lane = threadIdx.x & 63;
  int row = blockIdx.x * 4 + wave;        // b*L + n
  int n = row % L;
  int b = row / L;
  int gi = (n >= NPTS) ? 1 : 0;
  int nn = n - gi * NPTS;
  int src = gi ? ot[b * NPTS + nn] : oh[b * NPTS + nn];
  const float* xp = x + ((size_t)b * NPTS + src) * 3;
  float p0 = xp[0], p1 = xp[1], p2 = xp[2];
  int e0 = lane, e1 = lane + 64;
  float v0 = pe_b[e0] + p0 * pe_w[e0 * 3] + p1 * pe_w[e0 * 3 + 1] + p2 * pe_w[e0 * 3 + 2];
  float v1 = pe_b[e1] + p0 * pe_w[e1 * 3] + p1 * pe_w[e1 * 3 + 1] + p2 * pe_w[e1 * 3 + 2];
  v0 = v0 * gamma[gi * E + e0] + beta[gi * E + e0];
  v1 = v1 * gamma[gi * E + e1] + beta[gi * E + e1];
  size_t base = (size_t)row * E;
  h[base + e0] = v0;
  h[base + e1] = v1;
  // LN
  float s1 = v0 + v1, s2 = v0 * v0 + v1 * v1;
  #pragma unroll
  for (int off = 32; off > 0; off >>= 1) {
    s1 += __shfl_xor(s1, off);
    s2 += __shfl_xor(s2, off);
  }
  float m = s1 * (1.0f / E);
  float var = s2 * (1.0f / E) - m * m;
  float inv = rsqrtf(var + 1e-5f);
  float o0 = (v0 - m) * inv * g[e0] + bb[e0];
  float o1 = (v1 - m) * inv * g[e1] + bb[e1];
  u16 h0 = f2bf(o0), h1 = f2bf(o1);
  dhi[base + e0] = h0; dhi[base + e1] = h1;
  dlo[base + e0] = f2bf(o0 - bf2f(h0));
  dlo[base + e1] = f2bf(o1 - bf2f(h1));
}

// ---------------------------------------------------------------- split all weights (inproj + outw + xproj) in one dispatch
__global__ void split_all(const float* __restrict__ inproj, const float* __restrict__ outw,
                          const float* __restrict__ xw,
                          u16* __restrict__ wihi, u16* __restrict__ wilo,
                          u16* __restrict__ wohi, u16* __restrict__ wolo,
                          u16* __restrict__ wxhi, u16* __restrict__ wxlo) {
  const int n1 = NBLK * 2 * DI * E;
  const int n2 = NBLK * E * DI;
  const int n3 = NBLK * XDW * DI;
  int i = blockIdx.x * 256 + threadIdx.x;
  if (i < n1) {
    float v = inproj[i];
    u16 h = f2bf(v);
    wihi[i] = h; wilo[i] = f2bf(v - bf2f(h));
  } else if (i < n1 + n2) {
    int j = i - n1;
    float v = outw[j];
    u16 h = f2bf(v);
    wohi[j] = h; wolo[j] = f2bf(v - bf2f(h));
  } else if (i < n1 + n2 + n3) {
    int j = i - n1 - n2;
    float v = xw[j];
    u16 h = f2bf(v);
    wxhi[j] = h; wxlo[j] = f2bf(v - bf2f(h));
  }
}

// ---------------------------------------------------------------- LDS-staged split-bf16 MFMA GEMM (inproj)
template<int BN, int ACC>
__global__ __launch_bounds__(256)
void mfma_gemm_lds(const u16* __restrict__ Ahi, const u16* __restrict__ Alo,
                   const u16* __restrict__ Bhi, const u16* __restrict__ Blo,
                   float* __restrict__ C, int M, int N, int K, int ldc) {
  constexpr int BM = 128, BK = 64, PITCH = 72;
  constexpr int MSUB = (BN == 128) ? 4 : 2;
  constexpr int NSUB = 4;
  __shared__ u16 sA[2][BM][PITCH];
  __shared__ u16 sB[2][BN][PITCH];
  int tid = threadIdx.x;
  int wave = tid >> 6, lane = tid & 63, quad = lane >> 4, l16 = lane & 15;
  int rowBase = blockIdx.x * BM, colBase = blockIdx.y * BN;
  int wrow = (BN == 128) ? (wave >> 1) * 64 : wave * 32;
  int wcol = (BN == 128) ? (wave & 1) * 64 : 0;
  f32x4v acc[MSUB][NSUB] = {};
  for (int k0 = 0; k0 < K; k0 += BK) {
    #pragma unroll
    for (int hl = 0; hl < 2; hl++) {
      const u16* srcA = hl ? Alo : Ahi;
      #pragma unroll
      for (int c = 0; c < BM * 8 / 256; c++) {
        int ch = c * 256 + tid;
        int row = ch >> 3, kc = ch & 7;
        float4 v = *(const float4*)(srcA + (size_t)(rowBase + row) * K + k0 + kc * 8);
        *(float4*)&sA[hl][row][kc * 8] = v;
      }
      const u16* srcB = hl ? Blo : Bhi;
      #pragma unroll
      for (int c = 0; c < BN * 8 / 256; c++) {
        int ch = c * 256 + tid;
        int row = ch >> 3, kc = ch & 7;
        float4 v = *(const float4*)(srcB + (size_t)(colBase + row) * K + k0 + kc * 8);
        *(float4*)&sB[hl][row][kc * 8] = v;
      }
    }
    __syncthreads();
    short8 afh[MSUB][2], afl[MSUB][2];
    #pragma unroll
    for (int i = 0; i < MSUB; i++)
      #pragma unroll
      for (int kf = 0; kf < 2; kf++) {
        afh[i][kf] = *(const short8*)&sA[0][wrow + i * 16 + l16][kf * 32 + quad * 8];
        afl[i][kf] = *(const short8*)&sA[1][wrow + i * 16 + l16][kf * 32 + quad * 8];
      }
    #pragma unroll
    for (int j = 0; j < NSUB; j++)
      #pragma unroll
      for (int kf = 0; kf < 2; kf++) {
        short8 bh = *(const short8*)&sB[0][wcol + j * 16 + l16][kf * 32 + quad * 8];
        short8 bl = *(const short8*)&sB[1][wcol + j * 16 + l16][kf * 32 + quad * 8];
        #pragma unroll
        for (int i = 0; i < MSUB; i++) {
          acc[i][j] = __builtin_amdgcn_mfma_f32_16x16x32_bf16(afh[i][kf], bh, acc[i][j], 0, 0, 0);
          acc[i][j] = __builtin_amdgcn_mfma_f32_16x16x32_bf16(afh[i][kf], bl, acc[i][j], 0, 0, 0);
          acc[i][j] = __builtin_amdgcn_mfma_f32_16x16x32_bf16(afl[i][kf], bh, acc[i][j], 0, 0, 0);
        }
      }
    __syncthreads();
  }
  int orow0 = rowBase + wrow + quad * 4;
  #pragma unroll
  for (int i = 0; i < MSUB; i++) {
    #pragma unroll
    for (int j = 0; j < NSUB; j++) {
      int cc = colBase + wcol + j * 16 + l16;
      #pragma unroll
      for (int r = 0; r < 4; r++) {
        size_t idx = (size_t)(orow0 + i * 16 + r) * ldc + cc;
        if (ACC) C[idx] += acc[i][j][r];
        else     C[idx] = acc[i][j][r];
      }
    }
  }
}

// ---------------------------------------------------------------- scan pass A MEGA (lean, spill-free):
// conv+silu -> bf16 hi/lo LDS -> xproj MFMA (xsm LDS + xdbl global) -> chunk scan.
// exp powers via sequential running product (R8 form — binary tree regressed, R9).
__global__ __launch_bounds__(256, 2)
void scan_passA_cx(const float* __restrict__ uz,
                   const float* __restrict__ cw, const float* __restrict__ cb,
                   const u16* __restrict__ xwhi, const u16* __restrict__ xwlo,
                   const float* __restrict__ dtw, const float* __restrict__ dtb,
                   const float* __restrict__ A_log,
                   float* __restrict__ xdbl,
                   float* __restrict__ hloc, float* __restrict__ sumd) {
  constexpr int UPITCH = DI + 8;     // 264 u16 rows (16B aligned, conflict-free)
  constexpr int XP = 48;             // xsm pitch (covers padded 48 cols)
  __shared__ u16 sUhi[CH][UPITCH];   // 16896 B
  __shared__ u16 sUlo[CH][UPITCH];   // 16896 B
  __shared__ float xsm[CH][XP];      // 6144 B   (total ~40 KB)
  int b = blockIdx.x / NCH, c = blockIdx.x % NCH;
  int d = threadIdx.x;
  const size_t US = 2 * DI;
  const float* up = uz + ((size_t)b * L + c * CH) * US + d;
  float cw0 = cw[d * DCV], cw1 = cw[d * DCV + 1], cw2 = cw[d * DCV + 2], cw3 = cw[d * DCV + 3];
  float cbias = cb[d];
  float um0, um1, um2;
  if (c == 0) { um0 = um1 = um2 = 0.f; }
  else {
    um0 = up[-3 * (ptrdiff_t)US];
    um1 = up[-2 * (ptrdiff_t)US];
    um2 = up[-1 * (ptrdiff_t)US];
  }
  float ucur = up[0];
  #pragma unroll
  for (int j = 0; j < CH; j++) {
    float unext = (j + 1 < CH) ? up[(size_t)(j + 1) * US] : 0.f;
    float a = cbias + cw0 * um0 + cw1 * um1 + cw2 * um2 + cw3 * ucur;
    float v = a / (1.f + __expf(-a));
    um0 = um1; um1 = um2; um2 = ucur; ucur = unext;
    u16 hh = f2bf(v);
    sUhi[j][d] = hh;
    sUlo[j][d] = f2bf(v - bf2f(hh));
  }
  __syncthreads();
  // xproj MFMA: xdbl[32][40] = u[32][256] @ xw^T (4-term split = ~fp32)
  int wave = d >> 6, lane = d & 63, quad = lane >> 4, l16 = lane & 15;
  if (wave < 3) {                            // 3 n-tiles cover XDW=40 (pad to 48)
    int col = wave * 16 + l16;
    int colc = (col < XDW) ? col : 0;
    const u16* bhp = xwhi + (size_t)colc * DI;
    const u16* blp = xwlo + (size_t)colc * DI;
    f32x4v acc[2] = {};
    #pragma unroll
    for (int ks = 0; ks < DI / 32; ks++) {
      short8 bh = *(const short8*)(bhp + ks * 32 + quad * 8);
      short8 bl = *(const short8*)(blp + ks * 32 + quad * 8);
      #pragma unroll
      for (int i = 0; i < 2; i++) {
        short8 ah = *(const short8*)&sUhi[i * 16 + l16][ks * 32 + quad * 8];
        short8 al = *(const short8*)&sUlo[i * 16 + l16][ks * 32 + quad * 8];
        acc[i] = __builtin_amdgcn_mfma_f32_16x16x32_bf16(ah, bh, acc[i], 0, 0, 0);
        acc[i] = __builtin_amdgcn_mfma_f32_16x16x32_bf16(ah, bl, acc[i], 0, 0, 0);
        acc[i] = __builtin_amdgcn_mfma_f32_16x16x32_bf16(al, bh, acc[i], 0, 0, 0);
        acc[i] = __builtin_amdgcn_mfma_f32_16x16x32_bf16(al, bl, acc[i], 0, 0, 0);
      }
    }
    size_t rbase = (size_t)b * L + c * CH;
    #pragma unroll
    for (int i = 0; i < 2; i++) {
      #pragma unroll
      for (int r = 0; r < 4; r++) {
        int row = i * 16 + quad * 4 + r;
        xsm[row][col] = acc[i][r];
        if (col < XDW) xdbl[(rbase + row) * XDW + col] = acc[i][r];
      }
    }
  }
  __syncthreads();
  // chunk-local scan; utv/D/B all from LDS (no register arrays beyond st)
  const float* alp = A_log + d * DS;
  bool fastE = true;
  #pragma unroll
  for (int s = 0; s < DS; s++) {
    float av = -__expf(alp[s]);
    fastE = fastE && (fabsf(av + (float)(s + 1)) <= 1e-3f * (s + 1));
  }
  float4 wd0 = *(const float4*)(dtw + d * DRR);
  float4 wd1 = *(const float4*)(dtw + d * DRR + 4);
  float dbias = dtb[d];
  float st[DS] = {};
  float sd = 0.f;
  #pragma unroll
  for (int t0 = 0; t0 < CH; t0++) {
    float utv = bf2f(sUhi[t0][d]) + bf2f(sUlo[t0][d]);
    float4 D0 = *(const float4*)&xsm[t0][0];
    float4 D1 = *(const float4*)&xsm[t0][4];
    float v = dbias + D0.x * wd0.x + D0.y * wd0.y + D0.z * wd0.z + D0.w * wd0.w
                    + D1.x * wd1.x + D1.y * wd1.y + D1.z * wd1.z + D1.w * wd1.w;
    float dl = softplusf(v);
    sd += dl;
    float du = dl * utv;
    float4 B0 = *(const float4*)&xsm[t0][DRR + 0];
    float4 B1 = *(const float4*)&xsm[t0][DRR + 4];
    float4 B2 = *(const float4*)&xsm[t0][DRR + 8];
    float4 B3 = *(const float4*)&xsm[t0][DRR + 12];
    float Bv[DS] = {B0.x, B0.y, B0.z, B0.w, B1.x, B1.y, B1.z, B1.w,
                    B2.x, B2.y, B2.z, B2.w, B3.x, B3.y, B3.z, B3.w};
    if (fastE) {
      float e1 = __expf(-dl);
      float er = 1.f;
      #pragma unroll
      for (int s = 0; s < DS; s++) {
        er *= e1;
        st[s] = er * st[s] + du * Bv[s];
      }
    } else {
      #pragma unroll
      for (int s = 0; s < DS; s++) {
        float aa = __expf(-dl * __expf(alp[s]));
        st[s] = aa * st[s] + du * Bv[s];
      }
    }
  }
  size_t base = (((size_t)b * NCH + c) * DI + d) * DS;
  *(float4*)&hloc[base + 0]  = float4{st[0], st[1], st[2], st[3]};
  *(float4*)&hloc[base + 4]  = float4{st[4], st[5], st[6], st[7]};
  *(float4*)&hloc[base + 8]  = float4{st[8], st[9], st[10], st[11]};
  *(float4*)&hloc[base + 12] = float4{st[12], st[13], st[14], st[15]};
  sumd[((size_t)b * NCH + c) * DI + d] = sd;
}

// ---------------------------------------------------------------- scan pass B: coalesced serial scan, depth-16 prefetch
#define PB_G 16
__global__ __launch_bounds__(64)
void scan_passB(const float* __restrict__ A_log, const float* __restrict__ hloc,
                const float* __restrict__ sumd, float* __restrict__ hinit) {
  int tid = threadIdx.x;
  int dgroup = blockIdx.x % (DI / 4);
  int b = blockIdx.x / (DI / 4);
  int d = dgroup * 4 + (tid >> 4);
  int s = tid & 15;
  float Av = -__expf(A_log[d * DS + s]);
  size_t off = (size_t)b * NCH * DI * DS + dgroup * 64 + tid;
  size_t soff = (size_t)b * NCH * DI + d;
  const size_t HST = (size_t)DI * DS;
  float bv[PB_G], sd[PB_G], bvn[PB_G], sdn[PB_G];
  #pragma unroll
  for (int j = 0; j < PB_G; j++) {
    bv[j] = hloc[off + j * HST];
    sd[j] = sumd[soff + j * DI];
  }
  float X = 0.f;
  for (int g = 0; g < NCH / PB_G; g++) {
    if (g + 1 < NCH / PB_G) {
      #pragma unroll
      for (int j = 0; j < PB_G; j++) {
        bvn[j] = hloc[off + (j + PB_G) * HST];
        sdn[j] = sumd[soff + (j + PB_G) * DI];
      }
    }
    #pragma unroll
    for (int j = 0; j < PB_G; j++) {
      float a = __expf(Av * sd[j]);
      hinit[off + j * HST] = X;
      X = a * X + bv[j];
    }
    #pragma unroll
    for (int j = 0; j < PB_G; j++) { bv[j] = bvn[j]; sd[j] = sdn[j]; }
    off += PB_G * HST;
    soff += PB_G * DI;
  }
}

// ---------------------------------------------------------------- scan pass C MEGA (R8 form, best-measured):
// conv + dtproj + scan -> y (bf16 hi/lo in LDS) -> outproj MFMA -> residual -> LN
// VARIANT 0: h written back, LN -> bf16 hi/lo split (next block's input).
// VARIANT 1: h not written, LN -> per-block colsum partial (for final mean).
template<int VARIANT>
__global__ __launch_bounds__(256, 2)
void scan_passC_out(const float* __restrict__ uz, const float* __restrict__ xdbl,
                    const float* __restrict__ dtw, const float* __restrict__ dtb,
                    const float* __restrict__ A_log, const float* __restrict__ Dp,
                    const float* __restrict__ cw, const float* __restrict__ cb,
                    const float* __restrict__ hinit,
                    const u16* __restrict__ wohi, const u16* __restrict__ wolo,
                    float* __restrict__ h, const float* __restrict__ g,
                    const float* __restrict__ bb, u16* __restrict__ dhi,
                    u16* __restrict__ dlo, float* __restrict__ partial) {
  constexpr int YP = DI + 8;   // 264 u16 pitch (16B-aligned rows, proven conflict-free)
  constexpr int HP = E + 4;    // 132 f32 pitch
  int b = blockIdx.x / NCH, c = blockIdx.x % NCH;
  int d = threadIdx.x;
  __shared__ float Bsh[CH][DS];
  __shared__ float Csh[CH][DS];
  __shared__ float Dsh[CH][DRR];
  __shared__ u16 sYhi[CH][YP];   // 16896 B
  __shared__ u16 sYlo[CH][YP];   // 16896 B
  __shared__ float hsm[CH][HP];  // 16896 B
  __shared__ float red[4][E];    // 2048 B
  for (int i = threadIdx.x; i < CH * DS; i += 256) {
    int tt = i >> 4, s = i & 15;
    size_t rb = ((size_t)b * L + c * CH + tt) * XDW;
    Bsh[tt][s] = xdbl[rb + DRR + s];
    Csh[tt][s] = xdbl[rb + DRR + DS + s];
  }
  {
    int i = threadIdx.x;                    // CH*DRR == 256 exactly
    int td = i >> 3, q = i & 7;
    Dsh[td][q] = xdbl[((size_t)b * L + c * CH + td) * XDW + q];
  }
  const size_t US = 2 * DI;
  const float* up = uz + ((size_t)b * L + c * CH) * US + d;
  const float* zp = up + DI;
  float cw0 = cw[d * DCV], cw1 = cw[d * DCV + 1], cw2 = cw[d * DCV + 2], cw3 = cw[d * DCV + 3];
  float cbias = cb[d];
  float um0, um1, um2;
  if (c == 0) { um0 = um1 = um2 = 0.f; }
  else {
    um0 = up[-3 * (ptrdiff_t)US];
    um1 = up[-2 * (ptrdiff_t)US];
    um2 = up[-1 * (ptrdiff_t)US];
  }
  float ucur = up[0];
  float zcur = zp[0];
  float st[DS];
  size_t hbase = (((size_t)b * NCH + c) * DI + d) * DS;
  {
    float4 h0 = *(const float4*)&hinit[hbase + 0];
    float4 h1 = *(const float4*)&hinit[hbase + 4];
    float4 h2 = *(const float4*)&hinit[hbase + 8];
    float4 h3 = *(const float4*)&hinit[hbase + 12];
    st[0]=h0.x; st[1]=h0.y; st[2]=h0.z; st[3]=h0.w;
    st[4]=h1.x; st[5]=h1.y; st[6]=h1.z; st[7]=h1.w;
    st[8]=h2.x; st[9]=h2.y; st[10]=h2.z; st[11]=h2.w;
    st[12]=h3.x; st[13]=h3.y; st[14]=h3.z; st[15]=h3.w;
  }
  const float* alp = A_log + d * DS;
  bool fastE = true;
  #pragma unroll
  for (int s = 0; s < DS; s++) {
    float av = -__expf(alp[s]);
    fastE = fastE && (fabsf(av + (float)(s + 1)) <= 1e-3f * (s + 1));
  }
  float4 wd0 = *(const float4*)(dtw + d * DRR);
  float4 wd1 = *(const float4*)(dtw + d * DRR + 4);
  float dbias = dtb[d];
  float Dv = Dp[d];
  __syncthreads();
  #pragma unroll 8
  for (int t0 = 0; t0 < CH; t0++) {
    float unext = (t0 + 1 < CH) ? up[(size_t)(t0 + 1) * US] : 0.f;
    float znext = (t0 + 1 < CH) ? zp[(size_t)(t0 + 1) * US] : 0.f;
    float a = cbias + cw0 * um0 + cw1 * um1 + cw2 * um2 + cw3 * ucur;
    float utv = a / (1.f + __expf(-a));
    um0 = um1; um1 = um2; um2 = ucur; ucur = unext;
    float4 D0 = *(const float4*)&Dsh[t0][0];
    float4 D1 = *(const float4*)&Dsh[t0][4];
    float v = dbias + D0.x * wd0.x + D0.y * wd0.y + D0.z * wd0.z + D0.w * wd0.w
                    + D1.x * wd1.x + D1.y * wd1.y + D1.z * wd1.z + D1.w * wd1.w;
    float dl = softplusf(v);
    float du = dl * utv;
    float acc = Dv * utv;
    float4 B0 = *(const float4*)&Bsh[t0][0];
    float4 B1 = *(const float4*)&Bsh[t0][4];
    float4 B2 = *(const float4*)&Bsh[t0][8];
    float4 B3 = *(const float4*)&Bsh[t0][12];
    float4 C0 = *(const float4*)&Csh[t0][0];
    float4 C1 = *(const float4*)&Csh[t0][4];
    float4 C2 = *(const float4*)&Csh[t0][8];
    float4 C3 = *(const float4*)&Csh[t0][12];
    float Bv[DS] = {B0.x, B0.y, B0.z, B0.w, B1.x, B1.y, B1.z, B1.w,
                    B2.x, B2.y, B2.z, B2.w, B3.x, B3.y, B3.z, B3.w};
    float Cv[DS] = {C0.x, C0.y, C0.z, C0.w, C1.x, C1.y, C1.z, C1.w,
                    C2.x, C2.y, C2.z, C2.w, C3.x, C3.y, C3.z, C3.w};
    if (fastE) {
      float e1 = __expf(-dl);
      float er = 1.f;
      #pragma unroll
      for (int s = 0; s < DS; s++) {
        er *= e1;
        st[s] = er * st[s] + du * Bv[s];
        acc += st[s] * Cv[s];
      }
    } else {
      #pragma unroll
      for (int s = 0; s < DS; s++) {
        float aa = __expf(-dl * __expf(alp[s]));
        st[s] = aa * st[s] + du * Bv[s];
        acc += st[s] * Cv[s];
      }
    }
    float zz = zcur; zcur = znext;
    float yv = acc * (zz / (1.f + __expf(-zz)));
    u16 hh = f2bf(yv);
    sYhi[t0][d] = hh;
    sYlo[t0][d] = f2bf(yv - bf2f(hh));
  }
  __syncthreads();
  // outproj MFMA: out[32][128] = y[32][256] @ W^T, W = outw[E][DI] (hi/lo split, L2-hot)
  int wave = d >> 6, lane = d & 63, quad = lane >> 4, l16 = lane & 15;
  f32x4v oacc[2][2] = {};
  #pragma unroll
  for (int ks = 0; ks < DI / 32; ks++) {
    short8 a0h = *(const short8*)&sYhi[l16][ks * 32 + quad * 8];
    short8 a0l = *(const short8*)&sYlo[l16][ks * 32 + quad * 8];
    short8 a1h = *(const short8*)&sYhi[16 + l16][ks * 32 + quad * 8];
    short8 a1l = *(const short8*)&sYlo[16 + l16][ks * 32 + quad * 8];
    #pragma unroll
    for (int j = 0; j < 2; j++) {
      int col = wave * 32 + j * 16 + l16;
      short8 bh = *(const short8*)(wohi + (size_t)col * DI + ks * 32 + quad * 8);
      short8 bl = *(const short8*)(wolo + (size_t)col * DI + ks * 32 + quad * 8);
      oacc[0][j] = __builtin_amdgcn_mfma_f32_16x16x32_bf16(a0h, bh, oacc[0][j], 0, 0, 0);
      oacc[0][j] = __builtin_amdgcn_mfma_f32_16x16x32_bf16(a0h, bl, oacc[0][j], 0, 0, 0);
      oacc[0][j] = __builtin_amdgcn_mfma_f32_16x16x32_bf16(a0l, bh, oacc[0][j], 0, 0, 0);
      oacc[1][j] = __builtin_amdgcn_mfma_f32_16x16x32_bf16(a1h, bh, oacc[1][j], 0, 0, 0);
      oacc[1][j] = __builtin_amdgcn_mfma_f32_16x16x32_bf16(a1h, bl, oacc[1][j], 0, 0, 0);
      oacc[1][j] = __builtin_amdgcn_mfma_f32_16x16x32_bf16(a1l, bh, oacc[1][j], 0, 0, 0);
    }
  }
  // residual add, stage to LDS
  size_t rr0 = (size_t)b * L + c * CH;
  #pragma unroll
  for (int i = 0; i < 2; i++) {
    #pragma unroll
    for (int j = 0; j < 2; j++) {
      int col = wave * 32 + j * 16 + l16;
      #pragma unroll
      for (int r = 0; r < 4; r++) {
        int row = i * 16 + quad * 4 + r;
        float v = h[(rr0 + row) * E + col] + oacc[i][j][r];
        hsm[row][col] = v;
        if (VARIANT == 0) h[(rr0 + row) * E + col] = v;
      }
    }
  }
  __syncthreads();
  // LN: wave w handles rows w*8..w*8+7; lane covers cols lane, lane+64
  float g0 = g[lane], g1 = g[lane + 64], b0 = bb[lane], b1 = bb[lane + 64];
  float pa0 = 0.f, pa1 = 0.f;
  for (int jj = 0; jj < 8; jj++) {
    int row = wave * 8 + jj;
    float x0 = hsm[row][lane], x1 = hsm[row][lane + 64];
    float s1 = x0 + x1, s2 = x0 * x0 + x1 * x1;
    #pragma unroll
    for (int off = 32; off > 0; off >>= 1) {
      s1 += __shfl_xor(s1, off);
      s2 += __shfl_xor(s2, off);
    }
    float m = s1 * (1.0f / E);
    float var = s2 * (1.0f / E) - m * m;
    float inv = rsqrtf(var + 1e-5f);
    float o0 = (x0 - m) * inv * g0 + b0;
    float o1 = (x1 - m) * inv * g1 + b1;
    if (VARIANT == 0) {
      size_t base = (rr0 + row) * E;
      u16 h0 = f2bf(o0), h1 = f2bf(o1);
      dhi[base + lane]      = h0;
      dhi[base + lane + 64] = h1;
      dlo[base + lane]      = f2bf(o0 - bf2f(h0));
      dlo[base + lane + 64] = f2bf(o1 - bf2f(h1));
    } else {
      pa0 += o0; pa1 += o1;
    }
  }
  if (VARIANT == 1) {
    red[wave][lane]      = pa0;
    red[wave][lane + 64] = pa1;
    __syncthreads();
    if (wave == 0) {
      #pragma unroll
      for (int half = 0; half < 2; half++) {
        int e = lane + half * 64;
        partial[(size_t)blockIdx.x * E + e] =
            red[0][e] + red[1][e] + red[2][e] + red[3][e];
      }
    }
  }
}

// ---------------------------------------------------------------- final FC (fused reduce + GEMV): one block per batch
__global__ __launch_bounds__(256)
void fc_fused(const float* __restrict__ partial, const float* __restrict__ fcw,
              const float* __restrict__ fcb, float* __restrict__ out) {
  constexpr int WP = E + 4;                 // pad: kills same-bank stride-128 pattern
  __shared__ float red2[2][E];              // 1 KB
  __shared__ float hm[E];                   // 0.5 KB
  __shared__ float wsm[NC * WP];            // 21.1 KB
  int b = blockIdx.x;
  int tid = threadIdx.x;
  int e = tid & 127, half = tid >> 7;
  float s = 0.f;
  for (int gg = 0; gg < NCH / 2; gg++)
    s += partial[((size_t)b * NCH + half * (NCH / 2) + gg) * E + e];
  red2[half][e] = s;
  for (int i = tid; i < NC * E; i += 256) {
    int o = i >> 7, ee = i & 127;
    wsm[o * WP + ee] = fcw[i];
  }
  __syncthreads();
  if (tid < E) hm[tid] = red2[0][tid] + red2[1][tid];
  __syncthreads();
  if (tid < NC) {
    float acc = 0.f;
    #pragma unroll 8
    for (int ee = 0; ee < E; ee++) acc += hm[ee] * wsm[tid * WP + ee];
    out[b * NC + tid] = acc * (1.f / L) + fcb[tid];
  }
}

// ---------------------------------------------------------------- launch
extern "C" void kernel_launch(void* const* d_in, const int* in_sizes, int n_in,
                              void* d_out, int out_size, void* d_ws, size_t ws_size,
                              hipStream_t stream) {
  const float* x      = (const float*)d_in[0];
  const int*   oh     = (const int*)d_in[1];
  const int*   ot     = (const int*)d_in[2];
  const float* pe_w   = (const float*)d_in[3];
  const float* pe_b   = (const float*)d_in[4];
  const float* gamma  = (const float*)d_in[5];
  const float* beta   = (const float*)d_in[6];
  const float* ln_g   = (const float*)d_in[7];
  const float* ln_b   = (const float*)d_in[8];
  const float* inproj = (const float*)d_in[9];
  const float* conv_w = (const float*)d_in[10];
  const float* conv_b = (const float*)d_in[11];
  const float* xproj  = (const float*)d_in[12];
  const float* dtw    = (const float*)d_in[13];
  const float* dtb    = (const float*)d_in[14];
  const float* A_log  = (const float*)d_in[15];
  const float* Dp     = (const float*)d_in[16];
  const float* outw   = (const float*)d_in[17];
  const float* hn_g   = (const float*)d_in[18];
  const float* hn_b   = (const float*)d_in[19];
  const float* fc_w   = (const float*)d_in[20];
  const float* fc_b   = (const float*)d_in[21];
  float* out = (float*)d_out;

  char* ws = (char*)d_ws;
  size_t off = 0;
  auto alloc = [&](size_t bytes) { size_t o = off; off += (bytes + 255) & ~(size_t)255; return o; };
  float* h     = (float*)(ws + alloc((size_t)ROWS * E * 4));              // 8 MB
  u16*   xnhi  = (u16*)  (ws + alloc((size_t)ROWS * E * 2));              // 4 MB
  u16*   xnlo  = (u16*)  (ws + alloc((size_t)ROWS * E * 2));              // 4 MB
  float* uz    = (float*)(ws + alloc((size_t)ROWS * 2 * DI * 4));         // 32 MB
  float* xdbl  = (float*)(ws + alloc((size_t)ROWS * XDW * 4));            // 2.6 MB
  float* hloc  = (float*)(ws + alloc((size_t)BATCH * NCH * DI * DS * 4)); // 8.4 MB
  float* sumd  = (float*)(ws + alloc((size_t)BATCH * NCH * DI * 4));      // 0.5 MB
  u16*   wihi  = (u16*)  (ws + alloc((size_t)NBLK * 2 * DI * E * 2));     // 256 KB
  u16*   wilo  = (u16*)  (ws + alloc((size_t)NBLK * 2 * DI * E * 2));     // 256 KB
  u16*   wohi  = (u16*)  (ws + alloc((size_t)NBLK * E * DI * 2));         // 128 KB
  u16*   wolo  = (u16*)  (ws + alloc((size_t)NBLK * E * DI * 2));         // 128 KB
  u16*   wxhi  = (u16*)  (ws + alloc((size_t)NBLK * XDW * DI * 2));       // 40 KB
  u16*   wxlo  = (u16*)  (ws + alloc((size_t)NBLK * XDW * DI * 2));       // 40 KB
  float* partial = (float*)(ws + alloc((size_t)BATCH * NCH * E * 4));     // 256 KB
  float* hinit = hloc;    // passB: same-thread read-before-write per element

  embed_ln_split<<<ROWS / 4, 256, 0, stream>>>(x, oh, ot, pe_w, pe_b, gamma, beta,
                                               ln_g, ln_b, h, xnhi, xnlo);
  const int nsplit = NBLK * 2 * DI * E + NBLK * E * DI + NBLK * XDW * DI;
  split_all<<<(nsplit + 255) / 256, 256, 0, stream>>>(inproj, outw, xproj,
                                                      wihi, wilo, wohi, wolo, wxhi, wxlo);

  for (int i = 0; i < NBLK; i++) {
    // uz = xn @ inproj^T   (M=ROWS, N=2*DI=512, K=E=128)
    dim3 g1(ROWS / 128, (2 * DI) / 128);
    mfma_gemm_lds<128, 0><<<g1, 256, 0, stream>>>(xnhi, xnlo,
                                                  wihi + (size_t)i * 2 * DI * E, wilo + (size_t)i * 2 * DI * E,
                                                  uz, ROWS, 2 * DI, E, 2 * DI);

    // conv+silu+xproj+scanA fused (lean: no register arrays -> no spill)
    scan_passA_cx<<<BATCH * NCH, 256, 0, stream>>>(uz,
                                                   conv_w + (size_t)i * DI * DCV, conv_b + i * DI,
                                                   wxhi + (size_t)i * XDW * DI, wxlo + (size_t)i * XDW * DI,
                                                   dtw + (size_t)i * DI * DRR, dtb + i * DI,
                                                   A_log + (size_t)i * DI * DS,
                                                   xdbl, hloc, sumd);
    scan_passB<<<BATCH * (DI / 4), 64, 0, stream>>>(A_log + (size_t)i * DI * DS, hloc, sumd, hinit);

    // scan + outproj + residual + LN in one kernel (y never leaves LDS)
    if (i == 0) {
      scan_passC_out<0><<<BATCH * NCH, 256, 0, stream>>>(uz, xdbl, dtw + (size_t)i * DI * DRR, dtb + i * DI,
                                                         A_log + (size_t)i * DI * DS, Dp + i * DI,
                                                         conv_w + (size_t)i * DI * DCV, conv_b + i * DI,
                                                         hinit,
                                                         wohi + (size_t)i * E * DI, wolo + (size_t)i * E * DI,
                                                         h, ln_g + (i + 1) * E, ln_b + (i + 1) * E,
                                                         xnhi, xnlo, partial);
    } else {
      scan_passC_out<1><<<BATCH * NCH, 256, 0, stream>>>(uz, xdbl, dtw + (size_t)i * DI * DRR, dtb + i * DI,
                                                         A_log + (size_t)i * DI * DS, Dp + i * DI,
                                                         conv_w + (size_t)i * DI * DCV, conv_b + i * DI,
                                                         hinit,
                                                         wohi + (size_t)i * E * DI, wolo + (size_t)i * E * DI,
                                                         h, hn_g, hn_b,
                                                         xnhi, xnlo, partial);
    }
  }

  fc_fused<<<BATCH, 256, 0, stream>>>(partial, fc_w, fc_b, out);
}

// Round 11
// 261.422 us; speedup vs baseline: 1.1296x; 1.1296x over previous
//
#include <hip/hip_runtime.h>
#include <hip/hip_bf16.h>
#include <math.h>

// Problem constants (CompactPointMamba: B=4, N=2048, E=128)
#define BATCH 4
#define NPTS  2048
#define L     4096      // 2*NPTS after concat of hilbert/trans orders
#define E     128
#define DI    256       // E*EXP
#define DS    16
#define DRR   8         // (E+15)//16
#define DCV   4
#define NBLK  2
#define NC    40
#define XDW   40        // DR + 2*DS
#define ROWS  (BATCH*L) // 16384
#define CH    32        // scan chunk length (32 proven best: R5=276.6 vs R6 CH=16=290.5)
#define NCH   128       // L / CH

typedef unsigned short u16;
typedef short short8 __attribute__((ext_vector_type(8)));
typedef float f32x4v __attribute__((ext_vector_type(4)));

// bf16 round-to-nearest-even helpers
__device__ __forceinline__ u16 f2bf(float x) {
  unsigned u = __float_as_uint(x);
  u = u + 0x7FFFu + ((u >> 16) & 1u);
  return (u16)(u >> 16);
}
__device__ __forceinline__ float bf2f(u16 h) {
  return __uint_as_float(((unsigned)h) << 16);
}
// fast softplus: ln(1+e^x) = ln2 * log2(1 + 2^(x*log2e))
__device__ __forceinline__ float softplusf(float x) {
  if (x > 20.f) return x;
  float t = __builtin_amdgcn_exp2f(x * 1.44269504f);
  return 0.69314718f * __builtin_amdgcn_logf(1.f + t);
}

// ---------------------------------------------------------------- embed + LN(block0) + split, row per wave
__global__ void embed_ln_split(const float* __restrict__ x,
                               const int* __restrict__ oh, const int* __restrict__ ot,
                               const float* __restrict__ pe_w, const float* __restrict__ pe_b,
                               const float* __restrict__ gamma, const float* __restrict__ beta,
                               const float* __restrict__ g, const float* __restrict__ bb,
                               float* __restrict__ h, u16* __restrict__ dhi, u16* __restrict__ dlo) {
  int wave = threadIdx.x >> 6;
  int lane = threadIdx.x & 63;
  int row = blockIdx.x * 4 + wave;        // b*L + n
  int n = row % L;
  int b = row / L;
  int gi = (n >= NPTS) ? 1 : 0;
  int nn = n - gi * NPTS;
  int src = gi ? ot[b * NPTS + nn] : oh[b * NPTS + nn];
  const float* xp = x + ((size_t)b * NPTS + src) * 3;
  float p0 = xp[0], p1 = xp[1], p2 = xp[2];
  int e0 = lane, e1 = lane + 64;
  float v0 = pe_b[e0] + p0 * pe_w[e0 * 3] + p1 * pe_w[e0 * 3 + 1] + p2 * pe_w[e0 * 3 + 2];
  float v1 = pe_b[e1] + p0 * pe_w[e1 * 3] + p1 * pe_w[e1 * 3 + 1] + p2 * pe_w[e1 * 3 + 2];
  v0 = v0 * gamma[gi * E + e0] + beta[gi * E + e0];
  v1 = v1 * gamma[gi * E + e1] + beta[gi * E + e1];
  size_t base = (size_t)row * E;
  h[base + e0] = v0;
  h[base + e1] = v1;
  // LN
  float s1 = v0 + v1, s2 = v0 * v0 + v1 * v1;
  #pragma unroll
  for (int off = 32; off > 0; off >>= 1) {
    s1 += __shfl_xor(s1, off);
    s2 += __shfl_xor(s2, off);
  }
  float m = s1 * (1.0f / E);
  float var = s2 * (1.0f / E) - m * m;
  float inv = rsqrtf(var + 1e-5f);
  float o0 = (v0 - m) * inv * g[e0] + bb[e0];
  float o1 = (v1 - m) * inv * g[e1] + bb[e1];
  u16 h0 = f2bf(o0), h1 = f2bf(o1);
  dhi[base + e0] = h0; dhi[base + e1] = h1;
  dlo[base + e0] = f2bf(o0 - bf2f(h0));
  dlo[base + e1] = f2bf(o1 - bf2f(h1));
}

// ---------------------------------------------------------------- split all weights (inproj + outw + xproj) in one dispatch
__global__ void split_all(const float* __restrict__ inproj, const float* __restrict__ outw,
                          const float* __restrict__ xw,
                          u16* __restrict__ wihi, u16* __restrict__ wilo,
                          u16* __restrict__ wohi, u16* __restrict__ wolo,
                          u16* __restrict__ wxhi, u16* __restrict__ wxlo) {
  const int n1 = NBLK * 2 * DI * E;
  const int n2 = NBLK * E * DI;
  const int n3 = NBLK * XDW * DI;
  int i = blockIdx.x * 256 + threadIdx.x;
  if (i < n1) {
    float v = inproj[i];
    u16 h = f2bf(v);
    wihi[i] = h; wilo[i] = f2bf(v - bf2f(h));
  } else if (i < n1 + n2) {
    int j = i - n1;
    float v = outw[j];
    u16 h = f2bf(v);
    wohi[j] = h; wolo[j] = f2bf(v - bf2f(h));
  } else if (i < n1 + n2 + n3) {
    int j = i - n1 - n2;
    float v = xw[j];
    u16 h = f2bf(v);
    wxhi[j] = h; wxlo[j] = f2bf(v - bf2f(h));
  }
}

// ---------------------------------------------------------------- LDS-staged split-bf16 MFMA GEMM (inproj)
template<int BN, int ACC>
__global__ __launch_bounds__(256)
void mfma_gemm_lds(const u16* __restrict__ Ahi, const u16* __restrict__ Alo,
                   const u16* __restrict__ Bhi, const u16* __restrict__ Blo,
                   float* __restrict__ C, int M, int N, int K, int ldc) {
  constexpr int BM = 128, BK = 64, PITCH = 72;
  constexpr int MSUB = (BN == 128) ? 4 : 2;
  constexpr int NSUB = 4;
  __shared__ u16 sA[2][BM][PITCH];
  __shared__ u16 sB[2][BN][PITCH];
  int tid = threadIdx.x;
  int wave = tid >> 6, lane = tid & 63, quad = lane >> 4, l16 = lane & 15;
  int rowBase = blockIdx.x * BM, colBase = blockIdx.y * BN;
  int wrow = (BN == 128) ? (wave >> 1) * 64 : wave * 32;
  int wcol = (BN == 128) ? (wave & 1) * 64 : 0;
  f32x4v acc[MSUB][NSUB] = {};
  for (int k0 = 0; k0 < K; k0 += BK) {
    #pragma unroll
    for (int hl = 0; hl < 2; hl++) {
      const u16* srcA = hl ? Alo : Ahi;
      #pragma unroll
      for (int c = 0; c < BM * 8 / 256; c++) {
        int ch = c * 256 + tid;
        int row = ch >> 3, kc = ch & 7;
        float4 v = *(const float4*)(srcA + (size_t)(rowBase + row) * K + k0 + kc * 8);
        *(float4*)&sA[hl][row][kc * 8] = v;
      }
      const u16* srcB = hl ? Blo : Bhi;
      #pragma unroll
      for (int c = 0; c < BN * 8 / 256; c++) {
        int ch = c * 256 + tid;
        int row = ch >> 3, kc = ch & 7;
        float4 v = *(const float4*)(srcB + (size_t)(colBase + row) * K + k0 + kc * 8);
        *(float4*)&sB[hl][row][kc * 8] = v;
      }
    }
    __syncthreads();
    short8 afh[MSUB][2], afl[MSUB][2];
    #pragma unroll
    for (int i = 0; i < MSUB; i++)
      #pragma unroll
      for (int kf = 0; kf < 2; kf++) {
        afh[i][kf] = *(const short8*)&sA[0][wrow + i * 16 + l16][kf * 32 + quad * 8];
        afl[i][kf] = *(const short8*)&sA[1][wrow + i * 16 + l16][kf * 32 + quad * 8];
      }
    #pragma unroll
    for (int j = 0; j < NSUB; j++)
      #pragma unroll
      for (int kf = 0; kf < 2; kf++) {
        short8 bh = *(const short8*)&sB[0][wcol + j * 16 + l16][kf * 32 + quad * 8];
        short8 bl = *(const short8*)&sB[1][wcol + j * 16 + l16][kf * 32 + quad * 8];
        #pragma unroll
        for (int i = 0; i < MSUB; i++) {
          acc[i][j] = __builtin_amdgcn_mfma_f32_16x16x32_bf16(afh[i][kf], bh, acc[i][j], 0, 0, 0);
          acc[i][j] = __builtin_amdgcn_mfma_f32_16x16x32_bf16(afh[i][kf], bl, acc[i][j], 0, 0, 0);
          acc[i][j] = __builtin_amdgcn_mfma_f32_16x16x32_bf16(afl[i][kf], bh, acc[i][j], 0, 0, 0);
        }
      }
    __syncthreads();
  }
  int orow0 = rowBase + wrow + quad * 4;
  #pragma unroll
  for (int i = 0; i < MSUB; i++) {
    #pragma unroll
    for (int j = 0; j < NSUB; j++) {
      int cc = colBase + wcol + j * 16 + l16;
      #pragma unroll
      for (int r = 0; r < 4; r++) {
        size_t idx = (size_t)(orow0 + i * 16 + r) * ldc + cc;
        if (ACC) C[idx] += acc[i][j][r];
        else     C[idx] = acc[i][j][r];
      }
    }
  }
}

// ---------------------------------------------------------------- scan pass A MEGA (lean, spill-free):
// conv+silu -> bf16 hi/lo LDS -> xproj MFMA (xsm LDS + xdbl global) -> chunk scan.
// exp powers via sequential running product.
__global__ __launch_bounds__(256, 2)
void scan_passA_cx(const float* __restrict__ uz,
                   const float* __restrict__ cw, const float* __restrict__ cb,
                   const u16* __restrict__ xwhi, const u16* __restrict__ xwlo,
                   const float* __restrict__ dtw, const float* __restrict__ dtb,
                   const float* __restrict__ A_log,
                   float* __restrict__ xdbl,
                   float* __restrict__ hloc, float* __restrict__ sumd) {
  constexpr int UPITCH = DI + 8;     // 264 u16 rows (16B aligned, conflict-free)
  constexpr int XP = 48;             // xsm pitch (covers padded 48 cols)
  __shared__ u16 sUhi[CH][UPITCH];   // 16896 B
  __shared__ u16 sUlo[CH][UPITCH];   // 16896 B
  __shared__ float xsm[CH][XP];      // 6144 B   (total ~40 KB)
  int b = blockIdx.x / NCH, c = blockIdx.x % NCH;
  int d = threadIdx.x;
  const size_t US = 2 * DI;
  const float* up = uz + ((size_t)b * L + c * CH) * US + d;
  float cw0 = cw[d * DCV], cw1 = cw[d * DCV + 1], cw2 = cw[d * DCV + 2], cw3 = cw[d * DCV + 3];
  float cbias = cb[d];
  float um0, um1, um2;
  if (c == 0) { um0 = um1 = um2 = 0.f; }
  else {
    um0 = up[-3 * (ptrdiff_t)US];
    um1 = up[-2 * (ptrdiff_t)US];
    um2 = up[-1 * (ptrdiff_t)US];
  }
  float ucur = up[0];
  #pragma unroll
  for (int j = 0; j < CH; j++) {
    float unext = (j + 1 < CH) ? up[(size_t)(j + 1) * US] : 0.f;
    float a = cbias + cw0 * um0 + cw1 * um1 + cw2 * um2 + cw3 * ucur;
    float v = a / (1.f + __expf(-a));
    um0 = um1; um1 = um2; um2 = ucur; ucur = unext;
    u16 hh = f2bf(v);
    sUhi[j][d] = hh;
    sUlo[j][d] = f2bf(v - bf2f(hh));
  }
  __syncthreads();
  // xproj MFMA: xdbl[32][40] = u[32][256] @ xw^T (4-term split = ~fp32)
  int wave = d >> 6, lane = d & 63, quad = lane >> 4, l16 = lane & 15;
  if (wave < 3) {                            // 3 n-tiles cover XDW=40 (pad to 48)
    int col = wave * 16 + l16;
    int colc = (col < XDW) ? col : 0;
    const u16* bhp = xwhi + (size_t)colc * DI;
    const u16* blp = xwlo + (size_t)colc * DI;
    f32x4v acc[2] = {};
    #pragma unroll
    for (int ks = 0; ks < DI / 32; ks++) {
      short8 bh = *(const short8*)(bhp + ks * 32 + quad * 8);
      short8 bl = *(const short8*)(blp + ks * 32 + quad * 8);
      #pragma unroll
      for (int i = 0; i < 2; i++) {
        short8 ah = *(const short8*)&sUhi[i * 16 + l16][ks * 32 + quad * 8];
        short8 al = *(const short8*)&sUlo[i * 16 + l16][ks * 32 + quad * 8];
        acc[i] = __builtin_amdgcn_mfma_f32_16x16x32_bf16(ah, bh, acc[i], 0, 0, 0);
        acc[i] = __builtin_amdgcn_mfma_f32_16x16x32_bf16(ah, bl, acc[i], 0, 0, 0);
        acc[i] = __builtin_amdgcn_mfma_f32_16x16x32_bf16(al, bh, acc[i], 0, 0, 0);
        acc[i] = __builtin_amdgcn_mfma_f32_16x16x32_bf16(al, bl, acc[i], 0, 0, 0);
      }
    }
    size_t rbase = (size_t)b * L + c * CH;
    #pragma unroll
    for (int i = 0; i < 2; i++) {
      #pragma unroll
      for (int r = 0; r < 4; r++) {
        int row = i * 16 + quad * 4 + r;
        xsm[row][col] = acc[i][r];
        if (col < XDW) xdbl[(rbase + row) * XDW + col] = acc[i][r];
      }
    }
  }
  __syncthreads();
  // chunk-local scan; utv/D/B all from LDS (no register arrays beyond st)
  const float* alp = A_log + d * DS;
  bool fastE = true;
  #pragma unroll
  for (int s = 0; s < DS; s++) {
    float av = -__expf(alp[s]);
    fastE = fastE && (fabsf(av + (float)(s + 1)) <= 1e-3f * (s + 1));
  }
  float4 wd0 = *(const float4*)(dtw + d * DRR);
  float4 wd1 = *(const float4*)(dtw + d * DRR + 4);
  float dbias = dtb[d];
  float st[DS] = {};
  float sd = 0.f;
  #pragma unroll
  for (int t0 = 0; t0 < CH; t0++) {
    float utv = bf2f(sUhi[t0][d]) + bf2f(sUlo[t0][d]);
    float4 D0 = *(const float4*)&xsm[t0][0];
    float4 D1 = *(const float4*)&xsm[t0][4];
    float v = dbias + D0.x * wd0.x + D0.y * wd0.y + D0.z * wd0.z + D0.w * wd0.w
                    + D1.x * wd1.x + D1.y * wd1.y + D1.z * wd1.z + D1.w * wd1.w;
    float dl = softplusf(v);
    sd += dl;
    float du = dl * utv;
    float4 B0 = *(const float4*)&xsm[t0][DRR + 0];
    float4 B1 = *(const float4*)&xsm[t0][DRR + 4];
    float4 B2 = *(const float4*)&xsm[t0][DRR + 8];
    float4 B3 = *(const float4*)&xsm[t0][DRR + 12];
    float Bv[DS] = {B0.x, B0.y, B0.z, B0.w, B1.x, B1.y, B1.z, B1.w,
                    B2.x, B2.y, B2.z, B2.w, B3.x, B3.y, B3.z, B3.w};
    if (fastE) {
      float e1 = __expf(-dl);
      float er = 1.f;
      #pragma unroll
      for (int s = 0; s < DS; s++) {
        er *= e1;
        st[s] = er * st[s] + du * Bv[s];
      }
    } else {
      #pragma unroll
      for (int s = 0; s < DS; s++) {
        float aa = __expf(-dl * __expf(alp[s]));
        st[s] = aa * st[s] + du * Bv[s];
      }
    }
  }
  size_t base = (((size_t)b * NCH + c) * DI + d) * DS;
  *(float4*)&hloc[base + 0]  = float4{st[0], st[1], st[2], st[3]};
  *(float4*)&hloc[base + 4]  = float4{st[4], st[5], st[6], st[7]};
  *(float4*)&hloc[base + 8]  = float4{st[8], st[9], st[10], st[11]};
  *(float4*)&hloc[base + 12] = float4{st[12], st[13], st[14], st[15]};
  sumd[((size_t)b * NCH + c) * DI + d] = sd;
}

// ---------------------------------------------------------------- scan pass B: coalesced serial scan, depth-16 prefetch
#define PB_G 16
__global__ __launch_bounds__(64)
void scan_passB(const float* __restrict__ A_log, const float* __restrict__ hloc,
                const float* __restrict__ sumd, float* __restrict__ hinit) {
  int tid = threadIdx.x;
  int dgroup = blockIdx.x % (DI / 4);
  int b = blockIdx.x / (DI / 4);
  int d = dgroup * 4 + (tid >> 4);
  int s = tid & 15;
  float Av = -__expf(A_log[d * DS + s]);
  size_t off = (size_t)b * NCH * DI * DS + dgroup * 64 + tid;
  size_t soff = (size_t)b * NCH * DI + d;
  const size_t HST = (size_t)DI * DS;
  float bv[PB_G], sd[PB_G], bvn[PB_G], sdn[PB_G];
  #pragma unroll
  for (int j = 0; j < PB_G; j++) {
    bv[j] = hloc[off + j * HST];
    sd[j] = sumd[soff + j * DI];
  }
  float X = 0.f;
  for (int g = 0; g < NCH / PB_G; g++) {
    if (g + 1 < NCH / PB_G) {
      #pragma unroll
      for (int j = 0; j < PB_G; j++) {
        bvn[j] = hloc[off + (j + PB_G) * HST];
        sdn[j] = sumd[soff + (j + PB_G) * DI];
      }
    }
    #pragma unroll
    for (int j = 0; j < PB_G; j++) {
      float a = __expf(Av * sd[j]);
      hinit[off + j * HST] = X;
      X = a * X + bv[j];
    }
    #pragma unroll
    for (int j = 0; j < PB_G; j++) { bv[j] = bvn[j]; sd[j] = sdn[j]; }
    off += PB_G * HST;
    soff += PB_G * DI;
  }
}

// ---------------------------------------------------------------- scan pass C MEGA:
// conv + dtproj + scan -> y (bf16 hi/lo in LDS) -> outproj MFMA -> residual -> LN
// VARIANT 0: h written back, LN -> bf16 hi/lo split (next block's input).
// VARIANT 1: h not written, LN -> per-block colsum partial (for final mean).
template<int VARIANT>
__global__ __launch_bounds__(256, 2)
void scan_passC_out(const float* __restrict__ uz, const float* __restrict__ xdbl,
                    const float* __restrict__ dtw, const float* __restrict__ dtb,
                    const float* __restrict__ A_log, const float* __restrict__ Dp,
                    const float* __restrict__ cw, const float* __restrict__ cb,
                    const float* __restrict__ hinit,
                    const u16* __restrict__ wohi, const u16* __restrict__ wolo,
                    float* __restrict__ h, const float* __restrict__ g,
                    const float* __restrict__ bb, u16* __restrict__ dhi,
                    u16* __restrict__ dlo, float* __restrict__ partial) {
  constexpr int YP = DI + 8;   // 264 u16 pitch (16B-aligned rows, proven conflict-free)
  constexpr int HP = E + 4;    // 132 f32 pitch
  int b = blockIdx.x / NCH, c = blockIdx.x % NCH;
  int d = threadIdx.x;
  __shared__ float Bsh[CH][DS];
  __shared__ float Csh[CH][DS];
  __shared__ float Dsh[CH][DRR];
  __shared__ u16 sYhi[CH][YP];   // 16896 B
  __shared__ u16 sYlo[CH][YP];   // 16896 B
  __shared__ float hsm[CH][HP];  // 16896 B
  __shared__ float red[4][E];    // 2048 B
  for (int i = threadIdx.x; i < CH * DS; i += 256) {
    int tt = i >> 4, s = i & 15;
    size_t rb = ((size_t)b * L + c * CH + tt) * XDW;
    Bsh[tt][s] = xdbl[rb + DRR + s];
    Csh[tt][s] = xdbl[rb + DRR + DS + s];
  }
  {
    int i = threadIdx.x;                    // CH*DRR == 256 exactly
    int td = i >> 3, q = i & 7;
    Dsh[td][q] = xdbl[((size_t)b * L + c * CH + td) * XDW + q];
  }
  const size_t US = 2 * DI;
  const float* up = uz + ((size_t)b * L + c * CH) * US + d;
  const float* zp = up + DI;
  float cw0 = cw[d * DCV], cw1 = cw[d * DCV + 1], cw2 = cw[d * DCV + 2], cw3 = cw[d * DCV + 3];
  float cbias = cb[d];
  float um0, um1, um2;
  if (c == 0) { um0 = um1 = um2 = 0.f; }
  else {
    um0 = up[-3 * (ptrdiff_t)US];
    um1 = up[-2 * (ptrdiff_t)US];
    um2 = up[-1 * (ptrdiff_t)US];
  }
  float ucur = up[0];
  float zcur = zp[0];
  float st[DS];
  size_t hbase = (((size_t)b * NCH + c) * DI + d) * DS;
  {
    float4 h0 = *(const float4*)&hinit[hbase + 0];
    float4 h1 = *(const float4*)&hinit[hbase + 4];
    float4 h2 = *(const float4*)&hinit[hbase + 8];
    float4 h3 = *(const float4*)&hinit[hbase + 12];
    st[0]=h0.x; st[1]=h0.y; st[2]=h0.z; st[3]=h0.w;
    st[4]=h1.x; st[5]=h1.y; st[6]=h1.z; st[7]=h1.w;
    st[8]=h2.x; st[9]=h2.y; st[10]=h2.z; st[11]=h2.w;
    st[12]=h3.x; st[13]=h3.y; st[14]=h3.z; st[15]=h3.w;
  }
  const float* alp = A_log + d * DS;
  bool fastE = true;
  #pragma unroll
  for (int s = 0; s < DS; s++) {
    float av = -__expf(alp[s]);
    fastE = fastE && (fabsf(av + (float)(s + 1)) <= 1e-3f * (s + 1));
  }
  float4 wd0 = *(const float4*)(dtw + d * DRR);
  float4 wd1 = *(const float4*)(dtw + d * DRR + 4);
  float dbias = dtb[d];
  float Dv = Dp[d];
  __syncthreads();
  #pragma unroll 8
  for (int t0 = 0; t0 < CH; t0++) {
    float unext = (t0 + 1 < CH) ? up[(size_t)(t0 + 1) * US] : 0.f;
    float znext = (t0 + 1 < CH) ? zp[(size_t)(t0 + 1) * US] : 0.f;
    float a = cbias + cw0 * um0 + cw1 * um1 + cw2 * um2 + cw3 * ucur;
    float utv = a / (1.f + __expf(-a));
    um0 = um1; um1 = um2; um2 = ucur; ucur = unext;
    float4 D0 = *(const float4*)&Dsh[t0][0];
    float4 D1 = *(const float4*)&Dsh[t0][4];
    float v = dbias + D0.x * wd0.x + D0.y * wd0.y + D0.z * wd0.z + D0.w * wd0.w
                    + D1.x * wd1.x + D1.y * wd1.y + D1.z * wd1.z + D1.w * wd1.w;
    float dl = softplusf(v);
    float du = dl * utv;
    float acc = Dv * utv;
    float4 B0 = *(const float4*)&Bsh[t0][0];
    float4 B1 = *(const float4*)&Bsh[t0][4];
    float4 B2 = *(const float4*)&Bsh[t0][8];
    float4 B3 = *(const float4*)&Bsh[t0][12];
    float4 C0 = *(const float4*)&Csh[t0][0];
    float4 C1 = *(const float4*)&Csh[t0][4];
    float4 C2 = *(const float4*)&Csh[t0][8];
    float4 C3 = *(const float4*)&Csh[t0][12];
    float Bv[DS] = {B0.x, B0.y, B0.z, B0.w, B1.x, B1.y, B1.z, B1.w,
                    B2.x, B2.y, B2.z, B2.w, B3.x, B3.y, B3.z, B3.w};
    float Cv[DS] = {C0.x, C0.y, C0.z, C0.w, C1.x, C1.y, C1.z, C1.w,
                    C2.x, C2.y, C2.z, C2.w, C3.x, C3.y, C3.z, C3.w};
    if (fastE) {
      float e1 = __expf(-dl);
      float er = 1.f;
      #pragma unroll
      for (int s = 0; s < DS; s++) {
        er *= e1;
        st[s] = er * st[s] + du * Bv[s];
        acc += st[s] * Cv[s];
      }
    } else {
      #pragma unroll
      for (int s = 0; s < DS; s++) {
        float aa = __expf(-dl * __expf(alp[s]));
        st[s] = aa * st[s] + du * Bv[s];
        acc += st[s] * Cv[s];
      }
    }
    float zz = zcur; zcur = znext;
    float yv = acc * (zz / (1.f + __expf(-zz)));
    u16 hh = f2bf(yv);
    sYhi[t0][d] = hh;
    sYlo[t0][d] = f2bf(yv - bf2f(hh));
  }
  __syncthreads();
  // outproj MFMA: out[32][128] = y[32][256] @ W^T, W = outw[E][DI] (hi/lo split, L2-hot)
  int wave = d >> 6, lane = d & 63, quad = lane >> 4, l16 = lane & 15;
  f32x4v oacc[2][2] = {};
  #pragma unroll
  for (int ks = 0; ks < DI / 32; ks++) {
    short8 a0h = *(const short8*)&sYhi[l16][ks * 32 + quad * 8];
    short8 a0l = *(const short8*)&sYlo[l16][ks * 32 + quad * 8];
    short8 a1h = *(const short8*)&sYhi[16 + l16][ks * 32 + quad * 8];
    short8 a1l = *(const short8*)&sYlo[16 + l16][ks * 32 + quad * 8];
    #pragma unroll
    for (int j = 0; j < 2; j++) {
      int col = wave * 32 + j * 16 + l16;
      short8 bh = *(const short8*)(wohi + (size_t)col * DI + ks * 32 + quad * 8);
      short8 bl = *(const short8*)(wolo + (size_t)col * DI + ks * 32 + quad * 8);
      oacc[0][j] = __builtin_amdgcn_mfma_f32_16x16x32_bf16(a0h, bh, oacc[0][j], 0, 0, 0);
      oacc[0][j] = __builtin_amdgcn_mfma_f32_16x16x32_bf16(a0h, bl, oacc[0][j], 0, 0, 0);
      oacc[0][j] = __builtin_amdgcn_mfma_f32_16x16x32_bf16(a0l, bh, oacc[0][j], 0, 0, 0);
      oacc[1][j] = __builtin_amdgcn_mfma_f32_16x16x32_bf16(a1h, bh, oacc[1][j], 0, 0, 0);
      oacc[1][j] = __builtin_amdgcn_mfma_f32_16x16x32_bf16(a1h, bl, oacc[1][j], 0, 0, 0);
      oacc[1][j] = __builtin_amdgcn_mfma_f32_16x16x32_bf16(a1l, bh, oacc[1][j], 0, 0, 0);
    }
  }
  // residual add, stage to LDS
  size_t rr0 = (size_t)b * L + c * CH;
  #pragma unroll
  for (int i = 0; i < 2; i++) {
    #pragma unroll
    for (int j = 0; j < 2; j++) {
      int col = wave * 32 + j * 16 + l16;
      #pragma unroll
      for (int r = 0; r < 4; r++) {
        int row = i * 16 + quad * 4 + r;
        float v = h[(rr0 + row) * E + col] + oacc[i][j][r];
        hsm[row][col] = v;
        if (VARIANT == 0) h[(rr0 + row) * E + col] = v;
      }
    }
  }
  __syncthreads();
  // LN: wave w handles rows w*8..w*8+7; lane covers cols lane, lane+64
  float g0 = g[lane], g1 = g[lane + 64], b0 = bb[lane], b1 = bb[lane + 64];
  float pa0 = 0.f, pa1 = 0.f;
  for (int jj = 0; jj < 8; jj++) {
    int row = wave * 8 + jj;
    float x0 = hsm[row][lane], x1 = hsm[row][lane + 64];
    float s1 = x0 + x1, s2 = x0 * x0 + x1 * x1;
    #pragma unroll
    for (int off = 32; off > 0; off >>= 1) {
      s1 += __shfl_xor(s1, off);
      s2 += __shfl_xor(s2, off);
    }
    float m = s1 * (1.0f / E);
    float var = s2 * (1.0f / E) - m * m;
    float inv = rsqrtf(var + 1e-5f);
    float o0 = (x0 - m) * inv * g0 + b0;
    float o1 = (x1 - m) * inv * g1 + b1;
    if (VARIANT == 0) {
      size_t base = (rr0 + row) * E;
      u16 h0 = f2bf(o0), h1 = f2bf(o1);
      dhi[base + lane]      = h0;
      dhi[base + lane + 64] = h1;
      dlo[base + lane]      = f2bf(o0 - bf2f(h0));
      dlo[base + lane + 64] = f2bf(o1 - bf2f(h1));
    } else {
      pa0 += o0; pa1 += o1;
    }
  }
  if (VARIANT == 1) {
    red[wave][lane]      = pa0;
    red[wave][lane + 64] = pa1;
    __syncthreads();
    if (wave == 0) {
      #pragma unroll
      for (int half = 0; half < 2; half++) {
        int e = lane + half * 64;
        partial[(size_t)blockIdx.x * E + e] =
            red[0][e] + red[1][e] + red[2][e] + red[3][e];
      }
    }
  }
}

// ---------------------------------------------------------------- final FC stage 1: parallel reduction of partials
// one wave per (b,e): 512 waves = 128 blocks x 4 waves. lanes cover g2 and g2+64.
__global__ __launch_bounds__(256)
void fc_reduce(const float* __restrict__ partial, float* __restrict__ hmean) {
  int w = blockIdx.x * 4 + (threadIdx.x >> 6);   // 0..511 = b*E + e
  int lane = threadIdx.x & 63;
  int b = w >> 7, e = w & 127;
  float s = partial[((size_t)b * NCH + lane) * E + e]
          + partial[((size_t)b * NCH + 64 + lane) * E + e];
  #pragma unroll
  for (int off = 32; off > 0; off >>= 1) s += __shfl_xor(s, off);
  if (lane == 0) hmean[w] = s;
}

// ---------------------------------------------------------------- final FC stage 2: LDS-staged small GEMV
__global__ __launch_bounds__(256)
void fc_final(const float* __restrict__ hmean, const float* __restrict__ fcw,
              const float* __restrict__ fcb, float* __restrict__ out) {
  constexpr int WP = E + 4;                 // pad: kills same-bank stride-128 pattern
  __shared__ float hm[BATCH * E];           // 2 KB
  __shared__ float wsm[NC * WP];            // 21.1 KB
  for (int i = threadIdx.x; i < BATCH * E; i += 256) hm[i] = hmean[i];
  for (int i = threadIdx.x; i < NC * E; i += 256) {
    int o = i >> 7, e = i & 127;
    wsm[o * WP + e] = fcw[i];
  }
  __syncthreads();
  int i = threadIdx.x;
  if (i < BATCH * NC) {
    int b = i / NC, o = i % NC;
    float acc = 0.f;
    #pragma unroll 8
    for (int e = 0; e < E; e++) acc += hm[b * E + e] * wsm[o * WP + e];
    out[i] = acc * (1.f / L) + fcb[o];
  }
}

// ---------------------------------------------------------------- launch
extern "C" void kernel_launch(void* const* d_in, const int* in_sizes, int n_in,
                              void* d_out, int out_size, void* d_ws, size_t ws_size,
                              hipStream_t stream) {
  const float* x      = (const float*)d_in[0];
  const int*   oh     = (const int*)d_in[1];
  const int*   ot     = (const int*)d_in[2];
  const float* pe_w   = (const float*)d_in[3];
  const float* pe_b   = (const float*)d_in[4];
  const float* gamma  = (const float*)d_in[5];
  const float* beta   = (const float*)d_in[6];
  const float* ln_g   = (const float*)d_in[7];
  const float* ln_b   = (const float*)d_in[8];
  const float* inproj = (const float*)d_in[9];
  const float* conv_w = (const float*)d_in[10];
  const float* conv_b = (const float*)d_in[11];
  const float* xproj  = (const float*)d_in[12];
  const float* dtw    = (const float*)d_in[13];
  const float* dtb    = (const float*)d_in[14];
  const float* A_log  = (const float*)d_in[15];
  const float* Dp     = (const float*)d_in[16];
  const float* outw   = (const float*)d_in[17];
  const float* hn_g   = (const float*)d_in[18];
  const float* hn_b   = (const float*)d_in[19];
  const float* fc_w   = (const float*)d_in[20];
  const float* fc_b   = (const float*)d_in[21];
  float* out = (float*)d_out;

  char* ws = (char*)d_ws;
  size_t off = 0;
  auto alloc = [&](size_t bytes) { size_t o = off; off += (bytes + 255) & ~(size_t)255; return o; };
  float* h     = (float*)(ws + alloc((size_t)ROWS * E * 4));              // 8 MB
  u16*   xnhi  = (u16*)  (ws + alloc((size_t)ROWS * E * 2));              // 4 MB
  u16*   xnlo  = (u16*)  (ws + alloc((size_t)ROWS * E * 2));              // 4 MB
  float* uz    = (float*)(ws + alloc((size_t)ROWS * 2 * DI * 4));         // 32 MB
  float* xdbl  = (float*)(ws + alloc((size_t)ROWS * XDW * 4));            // 2.6 MB
  float* hloc  = (float*)(ws + alloc((size_t)BATCH * NCH * DI * DS * 4)); // 8.4 MB
  float* sumd  = (float*)(ws + alloc((size_t)BATCH * NCH * DI * 4));      // 0.5 MB
  u16*   wihi  = (u16*)  (ws + alloc((size_t)NBLK * 2 * DI * E * 2));     // 256 KB
  u16*   wilo  = (u16*)  (ws + alloc((size_t)NBLK * 2 * DI * E * 2));     // 256 KB
  u16*   wohi  = (u16*)  (ws + alloc((size_t)NBLK * E * DI * 2));         // 128 KB
  u16*   wolo  = (u16*)  (ws + alloc((size_t)NBLK * E * DI * 2));         // 128 KB
  u16*   wxhi  = (u16*)  (ws + alloc((size_t)NBLK * XDW * DI * 2));       // 40 KB
  u16*   wxlo  = (u16*)  (ws + alloc((size_t)NBLK * XDW * DI * 2));       // 40 KB
  float* partial = (float*)(ws + alloc((size_t)BATCH * NCH * E * 4));     // 256 KB
  float* hmean = (float*)(ws + alloc((size_t)BATCH * E * 4));             // 2 KB
  float* hinit = hloc;    // passB: same-thread read-before-write per element

  embed_ln_split<<<ROWS / 4, 256, 0, stream>>>(x, oh, ot, pe_w, pe_b, gamma, beta,
                                               ln_g, ln_b, h, xnhi, xnlo);
  const int nsplit = NBLK * 2 * DI * E + NBLK * E * DI + NBLK * XDW * DI;
  split_all<<<(nsplit + 255) / 256, 256, 0, stream>>>(inproj, outw, xproj,
                                                      wihi, wilo, wohi, wolo, wxhi, wxlo);

  for (int i = 0; i < NBLK; i++) {
    // uz = xn @ inproj^T   (M=ROWS, N=2*DI=512, K=E=128)
    dim3 g1(ROWS / 128, (2 * DI) / 128);
    mfma_gemm_lds<128, 0><<<g1, 256, 0, stream>>>(xnhi, xnlo,
                                                  wihi + (size_t)i * 2 * DI * E, wilo + (size_t)i * 2 * DI * E,
                                                  uz, ROWS, 2 * DI, E, 2 * DI);

    // conv+silu+xproj+scanA fused (lean: no register arrays -> no spill)
    scan_passA_cx<<<BATCH * NCH, 256, 0, stream>>>(uz,
                                                   conv_w + (size_t)i * DI * DCV, conv_b + i * DI,
                                                   wxhi + (size_t)i * XDW * DI, wxlo + (size_t)i * XDW * DI,
                                                   dtw + (size_t)i * DI * DRR, dtb + i * DI,
                                                   A_log + (size_t)i * DI * DS,
                                                   xdbl, hloc, sumd);
    scan_passB<<<BATCH * (DI / 4), 64, 0, stream>>>(A_log + (size_t)i * DI * DS, hloc, sumd, hinit);

    // scan + outproj + residual + LN in one kernel (y never leaves LDS)
    if (i == 0) {
      scan_passC_out<0><<<BATCH * NCH, 256, 0, stream>>>(uz, xdbl, dtw + (size_t)i * DI * DRR, dtb + i * DI,
                                                         A_log + (size_t)i * DI * DS, Dp + i * DI,
                                                         conv_w + (size_t)i * DI * DCV, conv_b + i * DI,
                                                         hinit,
                                                         wohi + (size_t)i * E * DI, wolo + (size_t)i * E * DI,
                                                         h, ln_g + (i + 1) * E, ln_b + (i + 1) * E,
                                                         xnhi, xnlo, partial);
    } else {
      scan_passC_out<1><<<BATCH * NCH, 256, 0, stream>>>(uz, xdbl, dtw + (size_t)i * DI * DRR, dtb + i * DI,
                                                         A_log + (size_t)i * DI * DS, Dp + i * DI,
                                                         conv_w + (size_t)i * DI * DCV, conv_b + i * DI,
                                                         hinit,
                                                         wohi + (size_t)i * E * DI, wolo + (size_t)i * E * DI,
                                                         h, hn_g, hn_b,
                                                         xnhi, xnlo, partial);
    }
  }

  fc_reduce<<<128, 256, 0, stream>>>(partial, hmean);
  fc_final<<<1, 256, 0, stream>>>(hmean, fc_w, fc_b, out);
}